// Round 3
// baseline (696.708 us; speedup 1.0000x reference)
//
#include <hip/hip_runtime.h>
#include <hip/hip_bf16.h>

// Problem constants
#define NROWS 8192   // rows of x / out
#define IN_F  4096   // K
#define OUT_F 4096   // output features

#define NPART 2048   // partial-sum slots (= prologue grid size)

typedef __attribute__((ext_vector_type(8))) __bf16 bf16x8;
typedef __attribute__((ext_vector_type(4))) float  f32x4;

// ---------------------------------------------------------------------------
// Static device scratch. Fully rewritten on every kernel_launch call.
// ---------------------------------------------------------------------------
__device__ double g_partial[NPART];                 // per-block |w| partial sums
__device__ ushort g_wq[(size_t)OUT_F * IN_F];       // 32 MiB ternary bf16 codes
__device__ ushort g_xb[(size_t)NROWS * IN_F];       // 64 MiB x in bf16

__device__ inline ushort f2bf_rne(float f) {
    unsigned u = __builtin_bit_cast(unsigned, f);
    unsigned r = u + 0x7FFFu + ((u >> 16) & 1u);
    return (ushort)(r >> 16);
}

// ---------------------------------------------------------------------------
// Kernel 1 (fused): x fp32->bf16 conversion  +  |w| fp64 partial reduction.
// No atomics: block b writes its partial to g_partial[b] (deterministic).
// ---------------------------------------------------------------------------
__global__ __launch_bounds__(256) void tl_prologue(const float* __restrict__ x,
                                                   const float* __restrict__ w) {
    const int idx = blockIdx.x * blockDim.x + threadIdx.x;
    const int stride = gridDim.x * blockDim.x;

    // --- x -> bf16 ---
    const float4* x4 = (const float4*)x;
    ushort4* o4 = (ushort4*)g_xb;
    for (int i = idx; i < NROWS * IN_F / 4; i += stride) {
        float4 v = x4[i];
        ushort4 q;
        q.x = f2bf_rne(v.x);
        q.y = f2bf_rne(v.y);
        q.z = f2bf_rne(v.z);
        q.w = f2bf_rne(v.w);
        o4[i] = q;
    }

    // --- sum |w| in fp64 ---
    double local = 0.0;
    const float4* w4 = (const float4*)w;
    for (int i = idx; i < OUT_F * IN_F / 4; i += stride) {
        float4 v = w4[i];
        local += (double)fabsf(v.x) + (double)fabsf(v.y) +
                 (double)fabsf(v.z) + (double)fabsf(v.w);
    }
    for (int off = 32; off > 0; off >>= 1)
        local += __shfl_down(local, off, 64);
    __shared__ double ssum[4];
    int lane = threadIdx.x & 63, wv = threadIdx.x >> 6;
    if (lane == 0) ssum[wv] = local;
    __syncthreads();
    if (threadIdx.x == 0)
        g_partial[blockIdx.x] = ssum[0] + ssum[1] + ssum[2] + ssum[3];
}

// ---------------------------------------------------------------------------
// Kernel 2: sum the 2048 partials (per block, L2-resident) then ternary-
// quantize w -> bf16 codes {0xBF80, 0, 0x3F80}.
// ---------------------------------------------------------------------------
__global__ __launch_bounds__(256) void tl_quantize_w(const float* __restrict__ w) {
    __shared__ double ssum[4];
    __shared__ double stotal;
    double s = 0.0;
    for (int i = threadIdx.x; i < NPART; i += 256) s += g_partial[i];
    for (int off = 32; off > 0; off >>= 1)
        s += __shfl_down(s, off, 64);
    int lane = threadIdx.x & 63, wv = threadIdx.x >> 6;
    if (lane == 0) ssum[wv] = s;
    __syncthreads();
    if (threadIdx.x == 0)
        stotal = ssum[0] + ssum[1] + ssum[2] + ssum[3];
    __syncthreads();
    const float thresh =
        (float)(0.5 * stotal / (double)((size_t)OUT_F * IN_F));

    const int idx = blockIdx.x * blockDim.x + threadIdx.x;
    const int stride = gridDim.x * blockDim.x;
    const float4* w4 = (const float4*)w;
    ushort4* q4 = (ushort4*)g_wq;
    for (int i = idx; i < OUT_F * IN_F / 4; i += stride) {
        float4 v = w4[i];
        ushort4 q;
        q.x = v.x > thresh ? 0x3F80u : (v.x < -thresh ? 0xBF80u : 0u);
        q.y = v.y > thresh ? 0x3F80u : (v.y < -thresh ? 0xBF80u : 0u);
        q.z = v.z > thresh ? 0x3F80u : (v.z < -thresh ? 0xBF80u : 0u);
        q.w = v.w > thresh ? 0x3F80u : (v.w < -thresh ? 0xBF80u : 0u);
        q4[i] = q;
    }
}

// ---------------------------------------------------------------------------
// Kernel 3: GEMM  C[m,n] = (sum_k A[m,k]*B[n,k] + bias[n]) * gamma
// A = g_xb [M,K] bf16, B = g_wq [N,K] bf16 (both K-major).
// 128x128 block tile, BK=32, 256 threads (4 waves, 2x2 of 64x64),
// global_load_lds width-16 staging, XOR bank swizzle on chunk placement:
//   global chunk g of row r lives at LDS slot (r, g ^ (r & 3)).
// ds_read_b128 fragments, mfma_f32_16x16x32_bf16 4x4 per wave.
// ---------------------------------------------------------------------------
#define GLD_LDS(gp, lp) \
    __builtin_amdgcn_global_load_lds( \
        (const __attribute__((address_space(1))) void*)(gp), \
        (__attribute__((address_space(3))) void*)(lp), 16, 0, 0)

__global__ __launch_bounds__(256) void tl_gemm_bt(
    const float* __restrict__ bias,
    const float* __restrict__ gamma_p,
    float* __restrict__ C) {
    constexpr int K = IN_F, N = OUT_F;
    constexpr int BK = 32;

    const ushort* __restrict__ A = g_xb;
    const ushort* __restrict__ B = g_wq;

    // LDS tiles: slot s (16 B) holds row r = s>>2, swizzled chunk i = s&3,
    // i.e. global chunk g = i ^ (r & 3). NO padding (scatter rule).
    __shared__ __align__(16) ushort As[128 * BK];
    __shared__ __align__(16) ushort Bs[128 * BK];

    const int tid  = threadIdx.x;
    const int lane = tid & 63;
    const int wave = tid >> 6;
    const int wm = (wave >> 1) * 64;   // wave row offset inside 128x128 tile
    const int wn = (wave & 1) * 64;    // wave col offset

    const int rowBase = blockIdx.y * 128;   // M
    const int colBase = blockIdx.x * 128;   // N

    f32x4 acc[4][4] = {};

    // Staging: thread tid owns LDS slots tid and 256+tid.
    // slot tid  -> (r0 = tid>>2,  i0 = tid&3)  -> global chunk g0 = i0 ^ (r0&3)
    // slot 256+tid -> row r0+64, same i0; (r0+64)&3 == r0&3 -> same g0.
    const int r0 = tid >> 2;
    const int g0 = (tid & 3) ^ (r0 & 3);
    const int cc0 = g0 * 8;   // element offset within row

    const ushort* A0 = A + (size_t)(rowBase + r0) * K + cc0;
    const ushort* A1 = A0 + (size_t)64 * K;
    const ushort* B0 = B + (size_t)(colBase + r0) * K + cc0;
    const ushort* B1 = B0 + (size_t)64 * K;

    char* lA = (char*)As;
    char* lB = (char*)Bs;
    const int lo0 = (wave * 64) * 16;          // wave-uniform LDS byte base
    const int lo1 = (256 + wave * 64) * 16;

    const int r16 = lane & 15;         // row-in-16 of this lane's fragment
    const int kg  = lane >> 4;         // k-group (chunk) 0..3
    const int sw  = ((kg ^ (r16 & 3)) * 8);  // swizzled chunk offset (ushorts)

    for (int kt = 0; kt < K; kt += BK) {
        GLD_LDS(A0 + kt, lA + lo0);
        GLD_LDS(A1 + kt, lA + lo1);
        GLD_LDS(B0 + kt, lB + lo0);
        GLD_LDS(B1 + kt, lB + lo1);
        __syncthreads();   // drains vmcnt -> LDS tiles complete

        bf16x8 af[4], bf[4];
#pragma unroll
        for (int i = 0; i < 4; ++i) {
            // (wm + i*16 + r16) & 3 == r16 & 3, so `sw` is the right swizzle
            af[i] = *(const bf16x8*)(As + (wm + i * 16 + r16) * BK + sw);
            bf[i] = *(const bf16x8*)(Bs + (wn + i * 16 + r16) * BK + sw);
        }
#pragma unroll
        for (int im = 0; im < 4; ++im)
#pragma unroll
            for (int in = 0; in < 4; ++in)
                acc[im][in] = __builtin_amdgcn_mfma_f32_16x16x32_bf16(
                    af[im], bf[in], acc[im][in], 0, 0, 0);
        __syncthreads();   // all waves done reading before next overwrite
    }

    // Epilogue. C/D layout: col = lane&15, row = (lane>>4)*4 + reg.
    const float g = *gamma_p;
    const int cq = (lane >> 4) * 4;
#pragma unroll
    for (int in = 0; in < 4; ++in) {
        const int col = colBase + wn + in * 16 + (lane & 15);
        const float bv = bias[col];
#pragma unroll
        for (int im = 0; im < 4; ++im) {
            const int rowb = rowBase + wm + im * 16 + cq;
#pragma unroll
            for (int r = 0; r < 4; ++r) {
                C[(size_t)(rowb + r) * N + col] = (acc[im][in][r] + bv) * g;
            }
        }
    }
}

// ---------------------------------------------------------------------------
// Launch: 3 kernels. No d_ws usage.
// ---------------------------------------------------------------------------
extern "C" void kernel_launch(void* const* d_in, const int* in_sizes, int n_in,
                              void* d_out, int out_size, void* d_ws, size_t ws_size,
                              hipStream_t stream) {
    const float* x     = (const float*)d_in[0];
    const float* w     = (const float*)d_in[1];
    const float* bias  = (const float*)d_in[2];
    const float* gamma = (const float*)d_in[3];
    float* out = (float*)d_out;
    (void)d_ws; (void)ws_size;

    tl_prologue<<<NPART, 256, 0, stream>>>(x, w);
    tl_quantize_w<<<1024, 256, 0, stream>>>(w);

    dim3 grid(OUT_F / 128, NROWS / 128);
    tl_gemm_bt<<<grid, 256, 0, stream>>>(bias, gamma, out);
}

// Round 4
// 465.200 us; speedup vs baseline: 1.4977x; 1.4977x over previous
//
#include <hip/hip_runtime.h>

// Problem constants
#define NROWS 8192   // rows of x / out
#define IN_F  4096   // K
#define OUT_F 4096   // output features
#define NPART 2048   // partial slots (= stats grid size)

typedef __attribute__((ext_vector_type(4))) int i32x4;

// ---------------------------------------------------------------------------
// Static device scratch. Fully rewritten on every kernel_launch call.
// ---------------------------------------------------------------------------
__device__ float  g_xmax_p[NPART];                  // per-block max|x|
__device__ double g_wsum_p[NPART];                  // per-block sum|w| (fp64)
__device__ float  g_s;                              // x quant scale = max|x|/127
__device__ signed char g_wq[(size_t)OUT_F * IN_F];  // 16 MiB ternary i8
__device__ signed char g_xq[(size_t)NROWS * IN_F];  // 32 MiB x in i8

// ---------------------------------------------------------------------------
// Kernel 1: stats pass — max|x| and sum|w| (fp64), per-block partials.
// No atomics: deterministic slot per block.
// ---------------------------------------------------------------------------
__global__ __launch_bounds__(256) void tl_stats(const float* __restrict__ x,
                                                const float* __restrict__ w) {
    const int idx = blockIdx.x * blockDim.x + threadIdx.x;
    const int stride = gridDim.x * blockDim.x;

    float lmax = 0.f;
    const float4* x4 = (const float4*)x;
    for (int i = idx; i < NROWS * IN_F / 4; i += stride) {
        float4 v = x4[i];
        lmax = fmaxf(lmax, fmaxf(fmaxf(fabsf(v.x), fabsf(v.y)),
                                 fmaxf(fabsf(v.z), fabsf(v.w))));
    }
    double lsum = 0.0;
    const float4* w4 = (const float4*)w;
    for (int i = idx; i < OUT_F * IN_F / 4; i += stride) {
        float4 v = w4[i];
        lsum += (double)fabsf(v.x) + (double)fabsf(v.y) +
                (double)fabsf(v.z) + (double)fabsf(v.w);
    }
    for (int off = 32; off > 0; off >>= 1) {
        lmax = fmaxf(lmax, __shfl_down(lmax, off, 64));
        lsum += __shfl_down(lsum, off, 64);
    }
    __shared__ float  smax[4];
    __shared__ double ssum[4];
    int lane = threadIdx.x & 63, wv = threadIdx.x >> 6;
    if (lane == 0) { smax[wv] = lmax; ssum[wv] = lsum; }
    __syncthreads();
    if (threadIdx.x == 0) {
        g_xmax_p[blockIdx.x] = fmaxf(fmaxf(smax[0], smax[1]), fmaxf(smax[2], smax[3]));
        g_wsum_p[blockIdx.x] = ssum[0] + ssum[1] + ssum[2] + ssum[3];
    }
}

// ---------------------------------------------------------------------------
// Kernel 2: finalize stats (per-block recompute from L2-resident partials),
// then quantize w -> ternary i8 and x -> i8 (16 elements / thread / iter,
// 16 B stores).
// ---------------------------------------------------------------------------
__global__ __launch_bounds__(256) void tl_quant(const float* __restrict__ x,
                                                const float* __restrict__ w) {
    float m = 0.f; double s = 0.0;
    for (int i = threadIdx.x; i < NPART; i += 256) {
        m = fmaxf(m, g_xmax_p[i]);
        s += g_wsum_p[i];
    }
    for (int off = 32; off > 0; off >>= 1) {
        m = fmaxf(m, __shfl_down(m, off, 64));
        s += __shfl_down(s, off, 64);
    }
    __shared__ float  smax[4];
    __shared__ double ssum[4];
    __shared__ float sh_thresh, sh_inv, sh_scale;
    int lane = threadIdx.x & 63, wv = threadIdx.x >> 6;
    if (lane == 0) { smax[wv] = m; ssum[wv] = s; }
    __syncthreads();
    if (threadIdx.x == 0) {
        double tot = ssum[0] + ssum[1] + ssum[2] + ssum[3];
        float  xm  = fmaxf(fmaxf(smax[0], smax[1]), fmaxf(smax[2], smax[3]));
        sh_thresh = (float)(0.5 * tot / (double)((size_t)OUT_F * IN_F));
        sh_scale  = xm / 127.f;
        sh_inv    = 127.f / xm;
    }
    __syncthreads();
    if (blockIdx.x == 0 && threadIdx.x == 0) g_s = sh_scale;
    const float thresh = sh_thresh, inv = sh_inv;

    const int idx = blockIdx.x * blockDim.x + threadIdx.x;
    const int stride = gridDim.x * blockDim.x;

    // --- w -> ternary i8 ---
    const float4* w4 = (const float4*)w;
    i32x4* wout = (i32x4*)g_wq;
    for (int i = idx; i < OUT_F * IN_F / 16; i += stride) {
        signed char q[16];
#pragma unroll
        for (int j = 0; j < 4; ++j) {
            float4 v = w4[i * 4 + j];
            q[4*j+0] = v.x > thresh ? 1 : (v.x < -thresh ? -1 : 0);
            q[4*j+1] = v.y > thresh ? 1 : (v.y < -thresh ? -1 : 0);
            q[4*j+2] = v.z > thresh ? 1 : (v.z < -thresh ? -1 : 0);
            q[4*j+3] = v.w > thresh ? 1 : (v.w < -thresh ? -1 : 0);
        }
        i32x4 val; __builtin_memcpy(&val, q, 16);
        wout[i] = val;
    }

    // --- x -> i8 (RNE, clamp) ---
    const float4* x4 = (const float4*)x;
    i32x4* xout = (i32x4*)g_xq;
    for (int i = idx; i < NROWS * IN_F / 16; i += stride) {
        signed char q[16];
#pragma unroll
        for (int j = 0; j < 4; ++j) {
            float4 v = x4[i * 4 + j];
            q[4*j+0] = (signed char)(int)rintf(fminf(fmaxf(v.x * inv, -127.f), 127.f));
            q[4*j+1] = (signed char)(int)rintf(fminf(fmaxf(v.y * inv, -127.f), 127.f));
            q[4*j+2] = (signed char)(int)rintf(fminf(fmaxf(v.z * inv, -127.f), 127.f));
            q[4*j+3] = (signed char)(int)rintf(fminf(fmaxf(v.w * inv, -127.f), 127.f));
        }
        i32x4 val; __builtin_memcpy(&val, q, 16);
        xout[i] = val;
    }
}

// ---------------------------------------------------------------------------
// Kernel 3: i8 GEMM  C[m,n] = (s * sum_k xq[m,k]*wq[n,k] + bias[n]) * gamma
// A = g_xq [M,K] i8, B = g_wq [N,K] i8 (both K-major).
// 128x128 block tile, BK=64 (same byte geometry as the verified bf16 BK=32
// kernel: 128 rows x 64 B tiles, 512 chunks), 256 threads (4 waves, 2x2 of
// 64x64), global_load_lds width-16 staging, ds_read_b128 fragments,
// mfma_i32_16x16x64_i8 4x4 per wave. 64 K-iters (half of bf16 version).
// ---------------------------------------------------------------------------
#define GLD_LDS(gp, lp) \
    __builtin_amdgcn_global_load_lds( \
        (const __attribute__((address_space(1))) void*)(gp), \
        (__attribute__((address_space(3))) void*)(lp), 16, 0, 0)

__global__ __launch_bounds__(256) void tl_gemm_i8(
    const float* __restrict__ bias,
    const float* __restrict__ gamma_p,
    float* __restrict__ C) {
    constexpr int K = IN_F, N = OUT_F;
    constexpr int BK = 64;

    const signed char* __restrict__ A = g_xq;
    const signed char* __restrict__ B = g_wq;

    // LDS: element (row,k) at row*BK + k. Chunk c (16 B) at byte c*16 —
    // matches wave-uniform base + lane*16 scatter. NO padding, NO swizzle.
    __shared__ __align__(16) signed char As[128 * BK];
    __shared__ __align__(16) signed char Bs[128 * BK];

    const int tid  = threadIdx.x;
    const int lane = tid & 63;
    const int wave = tid >> 6;
    const int wm = (wave >> 1) * 64;
    const int wn = (wave & 1) * 64;

    const int rowBase = blockIdx.y * 128;   // M
    const int colBase = blockIdx.x * 128;   // N

    i32x4 acc[4][4] = {};

    // Staging: thread tid owns chunks tid and 256+tid.
    // chunk c -> row c>>2, byte offset (c&3)*16 within the 64 B row.
    const int r0  = tid >> 2;
    const int cc0 = (tid & 3) * 16;

    const signed char* A0 = A + (size_t)(rowBase + r0) * K + cc0;
    const signed char* A1 = A0 + (size_t)64 * K;
    const signed char* B0 = B + (size_t)(colBase + r0) * K + cc0;
    const signed char* B1 = B0 + (size_t)64 * K;

    char* lA = (char*)As;
    char* lB = (char*)Bs;
    const int lo0 = (wave * 64) * 16;
    const int lo1 = (256 + wave * 64) * 16;

    const int kq  = (lane >> 4) * 16;  // k byte offset of this lane's fragment
    const int r16 = lane & 15;         // row-in-16

    for (int kt = 0; kt < K; kt += BK) {
        GLD_LDS(A0 + kt, lA + lo0);
        GLD_LDS(A1 + kt, lA + lo1);
        GLD_LDS(B0 + kt, lB + lo0);
        GLD_LDS(B1 + kt, lB + lo1);
        __syncthreads();   // drains vmcnt -> LDS tiles complete

        i32x4 af[4], bf[4];
#pragma unroll
        for (int i = 0; i < 4; ++i) {
            af[i] = *(const i32x4*)(As + (wm + i * 16 + r16) * BK + kq);
            bf[i] = *(const i32x4*)(Bs + (wn + i * 16 + r16) * BK + kq);
        }
#pragma unroll
        for (int im = 0; im < 4; ++im)
#pragma unroll
            for (int in = 0; in < 4; ++in)
                acc[im][in] = __builtin_amdgcn_mfma_i32_16x16x64_i8(
                    af[im], bf[in], acc[im][in], 0, 0, 0);
        __syncthreads();
    }

    // Epilogue. C/D layout (shape-determined): col = lane&15, row = (lane>>4)*4 + reg.
    const float g  = *gamma_p;
    const float sg = g_s * g;          // scale * gamma
    const int cq = (lane >> 4) * 4;
#pragma unroll
    for (int in = 0; in < 4; ++in) {
        const int col = colBase + wn + in * 16 + (lane & 15);
        const float bg = bias[col] * g;
#pragma unroll
        for (int im = 0; im < 4; ++im) {
            const int rowb = rowBase + wm + im * 16 + cq;
#pragma unroll
            for (int r = 0; r < 4; ++r) {
                C[(size_t)(rowb + r) * N + col] = (float)acc[im][in][r] * sg + bg;
            }
        }
    }
}

// ---------------------------------------------------------------------------
// Launch: 3 kernels. No d_ws usage.
// ---------------------------------------------------------------------------
extern "C" void kernel_launch(void* const* d_in, const int* in_sizes, int n_in,
                              void* d_out, int out_size, void* d_ws, size_t ws_size,
                              hipStream_t stream) {
    const float* x     = (const float*)d_in[0];
    const float* w     = (const float*)d_in[1];
    const float* bias  = (const float*)d_in[2];
    const float* gamma = (const float*)d_in[3];
    float* out = (float*)d_out;
    (void)d_ws; (void)ws_size;

    tl_stats<<<NPART, 256, 0, stream>>>(x, w);
    tl_quant<<<NPART, 256, 0, stream>>>(x, w);

    dim3 grid(OUT_F / 128, NROWS / 128);
    tl_gemm_i8<<<grid, 256, 0, stream>>>(bias, gamma, out);
}